// Round 14
// baseline (226.309 us; speedup 1.0000x reference)
//
#include <hip/hip_runtime.h>
#include <math.h>

#define NN 50000
#define NE 800000
#define NBUK 196          // ceil(50000/256), bucket = dst >> 8
#define PBLK 256          // partition blocks
#define EPB (NE / PBLK)   // 3125 edges per partition block

typedef __attribute__((ext_vector_type(8))) short bf16x8;
typedef __attribute__((ext_vector_type(4))) float f32x4;

__device__ __forceinline__ unsigned short f2b(float f) {
  union { float f; unsigned u; } v; v.f = f;
  unsigned r = v.u + 0x7FFF + ((v.u >> 16) & 1);  // RNE
  return (unsigned short)(r >> 16);
}
__device__ __forceinline__ float plo(unsigned v) {
  union { unsigned u; float f; } t; t.u = v << 16; return t.f;
}
__device__ __forceinline__ float phi(unsigned v) {
  union { unsigned u; float f; } t; t.u = v & 0xFFFF0000u; return t.f;
}

__device__ __forceinline__ int edge_val(const void* ei, long long idx, int is64) {
  if (is64) return (int)((const long long*)ei)[idx];
  return ((const int*)ei)[idx];
}

// ---- pass 1: per-block bucket histogram + fused weight transpose-cast ------
__global__ __launch_bounds__(256) void k_phist(const void* __restrict__ ei,
                                               int* __restrict__ bh,
                                               const float* __restrict__ W1,
                                               const float* __restrict__ W2,
                                               unsigned short* __restrict__ Wt1,
                                               unsigned short* __restrict__ Wt2) {
  if (threadIdx.x < 128) {
    int gi = blockIdx.x * 128 + threadIdx.x;
    int sel = gi >> 14;
    int j = gi & 16383;
    int k = j >> 7, n = j & 127;
    (sel ? Wt2 : Wt1)[n * 128 + k] = f2b((sel ? W2 : W1)[j]);
  }
  __shared__ int hist[NBUK];
  __shared__ int sflag;
  if (threadIdx.x < 64) {  // inline int64-vs-int32 detect (wave 0)
    unsigned v = ((const unsigned*)ei)[2 * threadIdx.x + 1];
    unsigned long long m = __ballot(v == 0u);
    if (threadIdx.x == 0) sflag = (m == ~0ull) ? 1 : 0;
  }
  if (threadIdx.x < NBUK) hist[threadIdx.x] = 0;
  __syncthreads();
  int is64 = sflag;
  int base = blockIdx.x * EPB;
  for (int e = base + threadIdx.x; e < base + EPB; e += 256) {
    int d = edge_val(ei, (long long)NE + e, is64);
    atomicAdd(&hist[d >> 8], 1);
  }
  __syncthreads();
  if (threadIdx.x < NBUK) bh[threadIdx.x * PBLK + blockIdx.x] = hist[threadIdx.x];
}

// ---- pass 2: per-bucket exclusive scan over the 256 block-counts -----------
__global__ __launch_bounds__(256) void k_pscanA(int* __restrict__ bh,
                                                int* __restrict__ colsum) {
  __shared__ int sh[256];
  int k = blockIdx.x, t = threadIdx.x;
  int v = bh[k * PBLK + t];
  sh[t] = v;
  __syncthreads();
  for (int s = 1; s < 256; s <<= 1) {
    int u = (t >= s) ? sh[t - s] : 0;
    __syncthreads();
    sh[t] += u;
    __syncthreads();
  }
  bh[k * PBLK + t] = sh[t] - v;  // exclusive
  if (t == 255) colsum[k] = sh[255];
}

// local inclusive scan of colsum into sh[256] (call with all 256 threads)
__device__ __forceinline__ void scan_colsum(const int* __restrict__ colsum,
                                            int* sh) {
  int t = threadIdx.x;
  sh[t] = (t < NBUK) ? colsum[t] : 0;
  __syncthreads();
  for (int s = 1; s < 256; s <<= 1) {
    int u = (t >= s) ? sh[t - s] : 0;
    __syncthreads();
    sh[t] += u;
    __syncthreads();
  }
}

// ---- pass 3: scatter edges into bucket-partitioned packed words ------------
// (bucket bases recomputed locally from colsum -> k_pscanB eliminated)
__global__ __launch_bounds__(256) void k_pscat(const void* __restrict__ ei,
                                               const int* __restrict__ bh,
                                               const int* __restrict__ colsum,
                                               unsigned* __restrict__ epk) {
  __shared__ int bs[256];
  __shared__ int cur[NBUK];
  __shared__ int sflag;
  if (threadIdx.x < 64) {
    unsigned v = ((const unsigned*)ei)[2 * threadIdx.x + 1];
    unsigned long long m = __ballot(v == 0u);
    if (threadIdx.x == 0) sflag = (m == ~0ull) ? 1 : 0;
  }
  scan_colsum(colsum, bs);
  if (threadIdx.x < NBUK) {
    int bstart = (threadIdx.x == 0) ? 0 : bs[threadIdx.x - 1];
    cur[threadIdx.x] = bstart + bh[threadIdx.x * PBLK + blockIdx.x];
  }
  __syncthreads();
  int is64 = sflag;
  int base = blockIdx.x * EPB;
  for (int e = base + threadIdx.x; e < base + EPB; e += 256) {
    int d = edge_val(ei, (long long)NE + e, is64);
    int s = edge_val(ei, e, is64);
    int p = atomicAdd(&cur[d >> 8], 1);
    epk[p] = (unsigned)s | ((unsigned)(d & 255) << 16);
  }
}

// ---- pass 4: per-bucket hist+scan -> off,dinv, then CSR16 fill (merged) ----
__global__ __launch_bounds__(256) void k_bofffill(const unsigned* __restrict__ epk,
                                                  const int* __restrict__ colsum,
                                                  int* __restrict__ off,
                                                  float* __restrict__ dinv,
                                                  unsigned short* __restrict__ csr16) {
  __shared__ int bs[256];
  __shared__ int hist[256];
  __shared__ int cur[256];
  int k = blockIdx.x, t = threadIdx.x;
  scan_colsum(colsum, bs);
  int e0 = (k == 0) ? 0 : bs[k - 1];
  int e1 = bs[k];
  hist[t] = 0;
  __syncthreads();
  for (int e = e0 + t; e < e1; e += 256)
    atomicAdd(&hist[(epk[e] >> 16) & 255], 1);
  __syncthreads();
  int myc = hist[t];
  for (int s = 1; s < 256; s <<= 1) {
    int u = (t >= s) ? hist[t - s] : 0;
    __syncthreads();
    hist[t] += u;
    __syncthreads();
  }
  int excl = hist[t] - myc;  // exclusive in-bucket prefix
  int node = k * 256 + t;
  if (node < NN) {
    off[node] = e0 + excl;
    dinv[node] = rsqrtf((float)(myc + 1));  // +1 self loop
  }
  cur[t] = e0 + excl;
  __syncthreads();
  for (int e = e0 + t; e < e1; e += 256) {
    unsigned pk = epk[e];
    int p = atomicAdd(&cur[(pk >> 16) & 255], 1);
    csr16[p] = (unsigned short)(pk & 0xFFFFu);
  }
  if (k == 0 && t == 0) off[NN] = NE;
}

// ---------------------------------------------------------------------------
// Out (QUARTER-MAJOR [4][M][32] bf16) = dinv[row] * (A @ W) via MFMA, swapped
// operands. Feature f = n*16 + kg*4 + j  ->  quarter q = n>>1.
// A_F32=1: A row-major f32 (x). A_F32=0: A quarter-major bf16 (H).
// ---------------------------------------------------------------------------
template <int A_F32>
__global__ __launch_bounds__(256, 2) void k_mgemm(const void* __restrict__ Ap,
                                                  const unsigned short* __restrict__ Wt,
                                                  const float* __restrict__ dinv,
                                                  unsigned short* __restrict__ Out,
                                                  int M) {
  int wid  = (blockIdx.x * blockDim.x + threadIdx.x) >> 6;
  int lane = threadIdx.x & 63;
  int nw   = (gridDim.x * blockDim.x) >> 6;
  int r  = lane & 15;
  int kg = lane >> 4;
  bf16x8 wf[8][4];
#pragma unroll
  for (int n = 0; n < 8; ++n)
#pragma unroll
    for (int kk = 0; kk < 4; ++kk)
      wf[n][kk] = *(const bf16x8*)&Wt[(n * 16 + r) * 128 + kk * 32 + kg * 8];
  int nstr = M >> 4;  // 50000 = 3125*16
  for (int s = wid; s < nstr; s += nw) {
    int row = s * 16 + r;
    bf16x8 xf[4];
    if (A_F32) {
      const float* Ar = (const float*)Ap + (long long)row * 128 + kg * 8;
#pragma unroll
      for (int kk = 0; kk < 4; ++kk) {
        float4 lo4 = *(const float4*)(Ar + kk * 32);
        float4 hi4 = *(const float4*)(Ar + kk * 32 + 4);
        bf16x8 t;
        t[0] = (short)f2b(lo4.x); t[1] = (short)f2b(lo4.y);
        t[2] = (short)f2b(lo4.z); t[3] = (short)f2b(lo4.w);
        t[4] = (short)f2b(hi4.x); t[5] = (short)f2b(hi4.y);
        t[6] = (short)f2b(hi4.z); t[7] = (short)f2b(hi4.w);
        xf[kk] = t;
      }
    } else {
      const unsigned short* Ar = (const unsigned short*)Ap;
#pragma unroll
      for (int kk = 0; kk < 4; ++kk)   // quarter kk holds features kk*32..+31
        xf[kk] = *(const bf16x8*)(Ar + ((size_t)(kk * NN + row) * 32) + kg * 8);
    }
    f32x4 acc[8];
#pragma unroll
    for (int n = 0; n < 8; ++n) acc[n] = (f32x4){0.f, 0.f, 0.f, 0.f};
#pragma unroll
    for (int kk = 0; kk < 4; ++kk)
#pragma unroll
      for (int n = 0; n < 8; ++n)
        acc[n] = __builtin_amdgcn_mfma_f32_16x16x32_bf16(wf[n][kk], xf[kk], acc[n], 0, 0, 0);
    float dv = dinv[row];
#pragma unroll
    for (int n = 0; n < 8; ++n) {
      int q = n >> 1;
      unsigned short* Or = Out + ((size_t)(q * NN + row) * 32) + (n & 1) * 16 + kg * 4;
      uint2 o;
      o.x = (unsigned)f2b(acc[n][0] * dv) | ((unsigned)f2b(acc[n][1] * dv) << 16);
      o.y = (unsigned)f2b(acc[n][2] * dv) | ((unsigned)f2b(acc[n][3] * dv) << 16);
      *(uint2*)Or = o;
    }
  }
}

// ---------------------------------------------------------------------------
// Layer-1 aggregation: quarter-blocked SLOT structure (wave = 4 node-slots x
// 16 lanes), q = (blockIdx&7)>>1 XCD-pinned (FETCH 20.5MB verified, R10).
// out = relu(dinv*(sum Ts + Tself) + b), quarter-major bf16.
// ---------------------------------------------------------------------------
__global__ __launch_bounds__(256) void k_agg0(const unsigned short* __restrict__ Tb,
                                              const int* __restrict__ off,
                                              const unsigned short* __restrict__ csr16,
                                              const float* __restrict__ dinv,
                                              const float* __restrict__ bias,
                                              unsigned* __restrict__ outp) {
  const unsigned* Tw = (const unsigned*)Tb;  // dword index (q*NN+s)*16 + li
  int bid  = blockIdx.x;
  int xcd  = bid & 7;
  int q    = xcd >> 1;
  int wb   = (bid >> 3) * 2 + (xcd & 1);   // 0..511 within quarter
  int wave = threadIdx.x >> 6;
  int lane = threadIdx.x & 63;
  int slot = lane >> 4;    // 0..3 node slots
  int li   = lane & 15;    // lane owns features q*32 + li*2, +1
  int gw   = wb * 4 + wave;                // 0..2047 wave id within quarter
  float2 bb = ((const float2*)bias)[q * 16 + li];
  const size_t qbase = (size_t)q * NN;
  for (int d0 = gw * 4; d0 < NN; d0 += 8192) {   // NN % 4 == 0
    int d = d0 + slot;
    int e0 = off[d], e1 = off[d + 1];
    unsigned v = Tw[(qbase + d) * 16 + li];      // self row
    float a0 = plo(v), a1 = phi(v);
    int e = e0;
    for (; e + 4 <= e1; e += 4) {
      int sA = csr16[e];
      int sB = csr16[e + 1];
      int sC = csr16[e + 2];
      int sD = csr16[e + 3];
      unsigned vA = Tw[(qbase + sA) * 16 + li];
      unsigned vB = Tw[(qbase + sB) * 16 + li];
      unsigned vC = Tw[(qbase + sC) * 16 + li];
      unsigned vD = Tw[(qbase + sD) * 16 + li];
      a0 += plo(vA); a1 += phi(vA);
      a0 += plo(vB); a1 += phi(vB);
      a0 += plo(vC); a1 += phi(vC);
      a0 += plo(vD); a1 += phi(vD);
    }
    for (; e < e1; ++e) {
      int sA = csr16[e];
      unsigned vA = Tw[(qbase + sA) * 16 + li];
      a0 += plo(vA); a1 += phi(vA);
    }
    float dv = dinv[d];
    a0 = fmaxf(fmaf(a0, dv, bb.x), 0.f);
    a1 = fmaxf(fmaf(a1, dv, bb.y), 0.f);
    outp[(qbase + d) * 16 + li] = (unsigned)f2b(a0) | ((unsigned)f2b(a1) << 16);
  }
}

// ---------------------------------------------------------------------------
// Layer-2 aggregation + 128->1 projection + sigmoid, FUSED (replaces
// k_agg<1> + part + k_fin). Full-row waves: 4 edge-groups x 16 lanes; lane li
// loads uint4 = 16B chunk (li&3) of quarter (li>>2) -> 16 lanes = full 256B
// row, 4 edges per wave-instruction (16 lines -- same line count, R12-proven
// invariant). Group-reduce, relu, dot(wout), lane-reduce, sigmoid, store.
// ---------------------------------------------------------------------------
__global__ __launch_bounds__(256) void k_agg1(const unsigned short* __restrict__ Tb,
                                              const int* __restrict__ off,
                                              const unsigned short* __restrict__ csr16,
                                              const float* __restrict__ dinv,
                                              const float* __restrict__ bias,
                                              const float* __restrict__ wout,
                                              const float* __restrict__ bout,
                                              float* __restrict__ out) {
  const uint4* Tw4 = (const uint4*)Tb;  // index (q*NN+s)*4 + w
  int wid  = (blockIdx.x * blockDim.x + threadIdx.x) >> 6;
  int nw   = (gridDim.x * blockDim.x) >> 6;
  int lane = threadIdx.x & 63;
  int grp  = lane >> 4;    // 0..3 edge groups
  int li   = lane & 15;
  int q    = li >> 2;      // quarter
  int w    = li & 3;       // 16B chunk within quarter: features q*32+w*8..+7
  float4 bA = ((const float4*)bias)[q * 8 + w * 2];
  float4 bB = ((const float4*)bias)[q * 8 + w * 2 + 1];
  float4 wA = ((const float4*)wout)[q * 8 + w * 2];
  float4 wB = ((const float4*)wout)[q * 8 + w * 2 + 1];
  const size_t qbase = (size_t)q * NN;
  for (int d = wid; d < NN; d += nw) {
    int e0 = off[d], e1 = off[d + 1];
    int ne = e1 - e0;
    int np = ne >> 2, rem = ne & 3;
    // init: group 0 = self row; group g in 1..3 = tail edge (if g-1 < rem)
    int s_init = (grp == 0) ? d : ((grp - 1) < rem ? (int)csr16[e1 - 1 - (grp - 1)] : -1);
    float a0 = 0.f, a1 = 0.f, a2 = 0.f, a3 = 0.f, a4 = 0.f, a5 = 0.f, a6 = 0.f, a7 = 0.f;
    if (s_init >= 0) {
      uint4 v = Tw4[(qbase + s_init) * 4 + w];
      a0 = plo(v.x); a1 = phi(v.x); a2 = plo(v.y); a3 = phi(v.y);
      a4 = plo(v.z); a5 = phi(v.z); a6 = plo(v.w); a7 = phi(v.w);
    }
    int base = e0 + grp;
    for (int st = 0; st < np; ++st) {
      int s = csr16[base + 4 * st];
      uint4 v = Tw4[(qbase + s) * 4 + w];
      a0 += plo(v.x); a1 += phi(v.x); a2 += plo(v.y); a3 += phi(v.y);
      a4 += plo(v.z); a5 += phi(v.z); a6 += plo(v.w); a7 += phi(v.w);
    }
    // reduce over the 4 edge-groups (lanes grp*16+li)
    a0 += __shfl_xor(a0, 16, 64); a1 += __shfl_xor(a1, 16, 64);
    a2 += __shfl_xor(a2, 16, 64); a3 += __shfl_xor(a3, 16, 64);
    a4 += __shfl_xor(a4, 16, 64); a5 += __shfl_xor(a5, 16, 64);
    a6 += __shfl_xor(a6, 16, 64); a7 += __shfl_xor(a7, 16, 64);
    a0 += __shfl_xor(a0, 32, 64); a1 += __shfl_xor(a1, 32, 64);
    a2 += __shfl_xor(a2, 32, 64); a3 += __shfl_xor(a3, 32, 64);
    a4 += __shfl_xor(a4, 32, 64); a5 += __shfl_xor(a5, 32, 64);
    a6 += __shfl_xor(a6, 32, 64); a7 += __shfl_xor(a7, 32, 64);
    float dv = dinv[d];
    a0 = fmaxf(fmaf(a0, dv, bA.x), 0.f);
    a1 = fmaxf(fmaf(a1, dv, bA.y), 0.f);
    a2 = fmaxf(fmaf(a2, dv, bA.z), 0.f);
    a3 = fmaxf(fmaf(a3, dv, bA.w), 0.f);
    a4 = fmaxf(fmaf(a4, dv, bB.x), 0.f);
    a5 = fmaxf(fmaf(a5, dv, bB.y), 0.f);
    a6 = fmaxf(fmaf(a6, dv, bB.z), 0.f);
    a7 = fmaxf(fmaf(a7, dv, bB.w), 0.f);
    float r = a0 * wA.x + a1 * wA.y + a2 * wA.z + a3 * wA.w
            + a4 * wB.x + a5 * wB.y + a6 * wB.z + a7 * wB.w;
    r += __shfl_xor(r, 8, 64);
    r += __shfl_xor(r, 4, 64);
    r += __shfl_xor(r, 2, 64);
    r += __shfl_xor(r, 1, 64);
    if (lane == 0) out[d] = 1.f / (1.f + __expf(-(r + bout[0])));
  }
}

// ---------------------------------------------------------------------------
extern "C" void kernel_launch(void* const* d_in, const int* in_sizes, int n_in,
                              void* d_out, int out_size, void* d_ws, size_t ws_size,
                              hipStream_t stream) {
  const float* x  = (const float*)d_in[0];
  const void*  ei = d_in[1];
  const float* W1 = (const float*)d_in[2];
  const float* b1 = (const float*)d_in[3];
  const float* W2 = (const float*)d_in[4];
  const float* b2 = (const float*)d_in[5];
  const float* Wo = (const float*)d_in[6];
  const float* bo = (const float*)d_in[7];
  float* out = (float*)d_out;

  char* p = (char*)d_ws;
  auto alloc = [&](size_t bytes) {
    char* r = p;
    p += (bytes + 511) & ~(size_t)511;
    return r;
  };
  int*   bh     = (int*)alloc(sizeof(int) * NBUK * PBLK);
  int*   colsum = (int*)alloc(sizeof(int) * NBUK);
  int*   off    = (int*)alloc(sizeof(int) * (NN + 1));
  float* dinv   = (float*)alloc(sizeof(float) * NN);
  unsigned short* csr16 = (unsigned short*)alloc(sizeof(short) * NE);
  unsigned short* Wt1 = (unsigned short*)alloc(sizeof(short) * 128 * 128);
  unsigned short* Wt2 = (unsigned short*)alloc(sizeof(short) * 128 * 128);
  unsigned short* T   = (unsigned short*)alloc(sizeof(short) * (size_t)NN * 128);
  unsigned short* H   = (unsigned short*)alloc(sizeof(short) * (size_t)NN * 128);
  unsigned* epk = (unsigned*)T;  // 3.2 MB, dead before k_mgemm<1> writes T

  k_phist<<<PBLK, 256, 0, stream>>>(ei, bh, W1, W2, Wt1, Wt2);
  k_pscanA<<<NBUK, 256, 0, stream>>>(bh, colsum);
  k_pscat<<<PBLK, 256, 0, stream>>>(ei, bh, colsum, epk);
  k_bofffill<<<NBUK, 256, 0, stream>>>(epk, colsum, off, dinv, csr16);

  k_mgemm<1><<<512, 256, 0, stream>>>(x, Wt1, dinv, T, NN);
  k_agg0<<<2048, 256, 0, stream>>>(T, off, csr16, dinv, b1, (unsigned*)H);
  k_mgemm<0><<<512, 256, 0, stream>>>(H, Wt2, dinv, T, NN);
  k_agg1<<<2048, 256, 0, stream>>>(T, off, csr16, dinv, b2, Wo, bo, out);
}

// Round 15
// 214.520 us; speedup vs baseline: 1.0550x; 1.0550x over previous
//
#include <hip/hip_runtime.h>
#include <math.h>

#define NN 50000
#define NE 800000
#define NBUK 196          // ceil(50000/256), bucket = dst >> 8
#define PBLK 256          // partition blocks
#define EPB (NE / PBLK)   // 3125 edges per partition block

typedef __attribute__((ext_vector_type(8))) short bf16x8;
typedef __attribute__((ext_vector_type(4))) float f32x4;

__device__ __forceinline__ unsigned short f2b(float f) {
  union { float f; unsigned u; } v; v.f = f;
  unsigned r = v.u + 0x7FFF + ((v.u >> 16) & 1);  // RNE
  return (unsigned short)(r >> 16);
}
__device__ __forceinline__ float plo(unsigned v) {
  union { unsigned u; float f; } t; t.u = v << 16; return t.f;
}
__device__ __forceinline__ float phi(unsigned v) {
  union { unsigned u; float f; } t; t.u = v & 0xFFFF0000u; return t.f;
}

__device__ __forceinline__ int edge_val(const void* ei, long long idx, int is64) {
  if (is64) return (int)((const long long*)ei)[idx];
  return ((const int*)ei)[idx];
}

// ---- pass 1: per-block bucket histogram; bh bucket-major [NBUK][PBLK] ------
__global__ __launch_bounds__(256) void k_phist(const void* __restrict__ ei,
                                               int* __restrict__ bh) {
  __shared__ int hist[NBUK];
  __shared__ int sflag;
  if (threadIdx.x < 64) {  // inline int64-vs-int32 detect (wave 0)
    unsigned v = ((const unsigned*)ei)[2 * threadIdx.x + 1];
    unsigned long long m = __ballot(v == 0u);
    if (threadIdx.x == 0) sflag = (m == ~0ull) ? 1 : 0;
  }
  if (threadIdx.x < NBUK) hist[threadIdx.x] = 0;
  __syncthreads();
  int is64 = sflag;
  int base = blockIdx.x * EPB;
  for (int e = base + threadIdx.x; e < base + EPB; e += 256) {
    int d = edge_val(ei, (long long)NE + e, is64);
    atomicAdd(&hist[d >> 8], 1);
  }
  __syncthreads();
  if (threadIdx.x < NBUK) bh[threadIdx.x * PBLK + blockIdx.x] = hist[threadIdx.x];
}

// ---- pass 2a: per-bucket exclusive scan over the 256 block-counts ----------
__global__ __launch_bounds__(256) void k_pscanA(int* __restrict__ bh,
                                                int* __restrict__ colsum) {
  __shared__ int sh[256];
  int k = blockIdx.x, t = threadIdx.x;
  int v = bh[k * PBLK + t];
  sh[t] = v;
  __syncthreads();
  for (int s = 1; s < 256; s <<= 1) {
    int u = (t >= s) ? sh[t - s] : 0;
    __syncthreads();
    sh[t] += u;
    __syncthreads();
  }
  bh[k * PBLK + t] = sh[t] - v;  // exclusive
  if (t == 255) colsum[k] = sh[255];
}

// ---- pass 2b: scan bucket totals -> bstart ---------------------------------
__global__ __launch_bounds__(256) void k_pscanB(const int* __restrict__ colsum,
                                                int* __restrict__ bstart) {
  __shared__ int sh[256];
  int t = threadIdx.x;
  sh[t] = (t < NBUK) ? colsum[t] : 0;
  __syncthreads();
  for (int s = 1; s < 256; s <<= 1) {
    int u = (t >= s) ? sh[t - s] : 0;
    __syncthreads();
    sh[t] += u;
    __syncthreads();
  }
  if (t <= NBUK) bstart[t] = (t == 0) ? 0 : sh[t - 1];
}

// ---- pass 3: scatter edges into bucket-partitioned packed words ------------
// epk = src (16b) | dst-in-bucket (8b) << 16      (NN < 65536)
__global__ __launch_bounds__(256) void k_pscat(const void* __restrict__ ei,
                                               const int* __restrict__ bh,
                                               const int* __restrict__ bstart,
                                               unsigned* __restrict__ epk) {
  __shared__ int cur[NBUK];
  __shared__ int sflag;
  if (threadIdx.x < 64) {
    unsigned v = ((const unsigned*)ei)[2 * threadIdx.x + 1];
    unsigned long long m = __ballot(v == 0u);
    if (threadIdx.x == 0) sflag = (m == ~0ull) ? 1 : 0;
  }
  if (threadIdx.x < NBUK)
    cur[threadIdx.x] = bstart[threadIdx.x] + bh[threadIdx.x * PBLK + blockIdx.x];
  __syncthreads();
  int is64 = sflag;
  int base = blockIdx.x * EPB;
  for (int e = base + threadIdx.x; e < base + EPB; e += 256) {
    int d = edge_val(ei, (long long)NE + e, is64);
    int s = edge_val(ei, e, is64);
    int p = atomicAdd(&cur[d >> 8], 1);
    epk[p] = (unsigned)s | ((unsigned)(d & 255) << 16);
  }
}

// ---- pass 4: per-bucket hist+scan -> off,dinv, then CSR16 fill (merged) ----
__global__ __launch_bounds__(256) void k_bofffill(const unsigned* __restrict__ epk,
                                                  const int* __restrict__ bstart,
                                                  int* __restrict__ off,
                                                  float* __restrict__ dinv,
                                                  unsigned short* __restrict__ csr16) {
  __shared__ int hist[256];
  __shared__ int cur[256];
  int k = blockIdx.x, t = threadIdx.x;
  hist[t] = 0;
  __syncthreads();
  int e0 = bstart[k], e1 = bstart[k + 1];
  for (int e = e0 + t; e < e1; e += 256)
    atomicAdd(&hist[(epk[e] >> 16) & 255], 1);
  __syncthreads();
  int myc = hist[t];
  for (int s = 1; s < 256; s <<= 1) {
    int u = (t >= s) ? hist[t - s] : 0;
    __syncthreads();
    hist[t] += u;
    __syncthreads();
  }
  int excl = hist[t] - myc;  // exclusive in-bucket prefix
  int node = k * 256 + t;
  if (node < NN) {
    off[node] = e0 + excl;
    dinv[node] = rsqrtf((float)(myc + 1));  // +1 self loop
  }
  cur[t] = e0 + excl;
  __syncthreads();
  for (int e = e0 + t; e < e1; e += 256) {
    unsigned pk = epk[e];
    int p = atomicAdd(&cur[(pk >> 16) & 255], 1);
    csr16[p] = (unsigned short)(pk & 0xFFFFu);
  }
  if (k == 0 && t == 0) off[NN] = NE;
}

// transpose-cast both weights W[k][n] f32 -> Wt[n][k] bf16 (parallel) --------
__global__ __launch_bounds__(256) void k_wt2(const float* __restrict__ W1,
                                             const float* __restrict__ W2,
                                             unsigned short* __restrict__ Wt1,
                                             unsigned short* __restrict__ Wt2) {
  int i = blockIdx.x * 256 + threadIdx.x;   // 0..32767
  int sel = i >> 14;
  int j = i & 16383;
  int k = j >> 7, n = j & 127;
  const float* W = sel ? W2 : W1;
  unsigned short* Wt = sel ? Wt2 : Wt1;
  Wt[n * 128 + k] = f2b(W[j]);
}

// ---------------------------------------------------------------------------
// Out[M][128] bf16 = dinv[row] * (A[M][128] @ W) via MFMA, swapped operands.
// D: col=lane&15 -> row in strip; row=4*(lane>>4)+reg -> feature (packed st).
// ---------------------------------------------------------------------------
template <int A_F32>
__global__ __launch_bounds__(256, 2) void k_mgemm(const void* __restrict__ Ap,
                                                  const unsigned short* __restrict__ Wt,
                                                  const float* __restrict__ dinv,
                                                  unsigned short* __restrict__ Out,
                                                  int M) {
  int wid  = (blockIdx.x * blockDim.x + threadIdx.x) >> 6;
  int lane = threadIdx.x & 63;
  int nw   = (gridDim.x * blockDim.x) >> 6;
  int r  = lane & 15;
  int kg = lane >> 4;
  bf16x8 wf[8][4];
#pragma unroll
  for (int n = 0; n < 8; ++n)
#pragma unroll
    for (int kk = 0; kk < 4; ++kk)
      wf[n][kk] = *(const bf16x8*)&Wt[(n * 16 + r) * 128 + kk * 32 + kg * 8];
  int nstr = M >> 4;  // 50000 = 3125*16
  for (int s = wid; s < nstr; s += nw) {
    int row = s * 16 + r;
    bf16x8 xf[4];
    if (A_F32) {
      const float* Ar = (const float*)Ap + (long long)row * 128 + kg * 8;
#pragma unroll
      for (int kk = 0; kk < 4; ++kk) {
        float4 lo4 = *(const float4*)(Ar + kk * 32);
        float4 hi4 = *(const float4*)(Ar + kk * 32 + 4);
        bf16x8 t;
        t[0] = (short)f2b(lo4.x); t[1] = (short)f2b(lo4.y);
        t[2] = (short)f2b(lo4.z); t[3] = (short)f2b(lo4.w);
        t[4] = (short)f2b(hi4.x); t[5] = (short)f2b(hi4.y);
        t[6] = (short)f2b(hi4.z); t[7] = (short)f2b(hi4.w);
        xf[kk] = t;
      }
    } else {
      const unsigned short* Ar = (const unsigned short*)Ap + (long long)row * 128 + kg * 8;
#pragma unroll
      for (int kk = 0; kk < 4; ++kk)
        xf[kk] = *(const bf16x8*)(Ar + kk * 32);
    }
    f32x4 acc[8];
#pragma unroll
    for (int n = 0; n < 8; ++n) acc[n] = (f32x4){0.f, 0.f, 0.f, 0.f};
#pragma unroll
    for (int kk = 0; kk < 4; ++kk)
#pragma unroll
      for (int n = 0; n < 8; ++n)
        acc[n] = __builtin_amdgcn_mfma_f32_16x16x32_bf16(wf[n][kk], xf[kk], acc[n], 0, 0, 0);
    float dv = dinv[row];
    unsigned short* Or = Out + (long long)row * 128 + kg * 4;
#pragma unroll
    for (int n = 0; n < 8; ++n) {
      uint2 o;
      o.x = (unsigned)f2b(acc[n][0] * dv) | ((unsigned)f2b(acc[n][1] * dv) << 16);
      o.y = (unsigned)f2b(acc[n][2] * dv) | ((unsigned)f2b(acc[n][3] * dv) << 16);
      *(uint2*)(Or + n * 16) = o;
    }
  }
}

// ---------------------------------------------------------------------------
// Aggregation over PRE-SCALED bf16 rows: one wave per dst node; half-wave
// pairing: lanes 0-31 process even edges, 32-63 odd edges; each lane loads
// uint2 (4 features). out[d] = relu( dinv[d]*(sum Ts[s] + Ts[d]) + b ).
// Init step: half 0 loads self row, half 1 loads the odd tail edge (if any).
// FINAL=1 fuses 128->1 projection + sigmoid.
// ---------------------------------------------------------------------------
template <int FINAL>
__global__ __launch_bounds__(256) void k_agg(const unsigned short* __restrict__ Tb,
                                             const int* __restrict__ off,
                                             const unsigned short* __restrict__ csr16,
                                             const float* __restrict__ dinv,
                                             const float* __restrict__ bias,
                                             const float* __restrict__ wout,
                                             const float* __restrict__ bout,
                                             void* __restrict__ outp) {
  const uint2* Tw2 = (const uint2*)Tb;  // 32 uint2 per 128-feature row
  int wid  = (blockIdx.x * blockDim.x + threadIdx.x) >> 6;
  int lane = threadIdx.x & 63;
  int half = lane >> 5;
  int li   = lane & 31;
  int nw   = (gridDim.x * blockDim.x) >> 6;
  float4 b4 = ((const float4*)bias)[li];
  float4 w4 = make_float4(0.f, 0.f, 0.f, 0.f);
  if (FINAL) w4 = ((const float4*)wout)[li];
  for (int d = wid; d < NN; d += nw) {
    int e0 = off[d], e1 = off[d + 1];
    int np  = (e1 - e0) >> 1;
    int rem = (e1 - e0) & 1;
    // init: half 0 takes the self row; half 1 takes the odd tail edge
    int s_init = half ? (rem ? (int)csr16[e1 - 1] : -1) : d;
    float a0 = 0.f, a1 = 0.f, a2 = 0.f, a3 = 0.f;
    if (s_init >= 0) {
      uint2 vv = Tw2[s_init * 32 + li];
      a0 = plo(vv.x); a1 = phi(vv.x); a2 = plo(vv.y); a3 = phi(vv.y);
    }
    int st = 0;
    int base = e0 + half;
    for (; st + 4 <= np; st += 4) {
      int s0 = csr16[base + 2 * st];
      int s1 = csr16[base + 2 * st + 2];
      int s2 = csr16[base + 2 * st + 4];
      int s3 = csr16[base + 2 * st + 6];
      uint2 v0 = Tw2[s0 * 32 + li];
      uint2 v1 = Tw2[s1 * 32 + li];
      uint2 v2 = Tw2[s2 * 32 + li];
      uint2 v3 = Tw2[s3 * 32 + li];
      a0 += plo(v0.x); a1 += phi(v0.x); a2 += plo(v0.y); a3 += phi(v0.y);
      a0 += plo(v1.x); a1 += phi(v1.x); a2 += plo(v1.y); a3 += phi(v1.y);
      a0 += plo(v2.x); a1 += phi(v2.x); a2 += plo(v2.y); a3 += phi(v2.y);
      a0 += plo(v3.x); a1 += phi(v3.x); a2 += plo(v3.y); a3 += phi(v3.y);
    }
    for (; st < np; ++st) {
      int s = csr16[base + 2 * st];
      uint2 vv = Tw2[s * 32 + li];
      a0 += plo(vv.x); a1 += phi(vv.x); a2 += plo(vv.y); a3 += phi(vv.y);
    }
    // cross-half reduce: both halves end with the full sum
    a0 += __shfl_xor(a0, 32, 64);
    a1 += __shfl_xor(a1, 32, 64);
    a2 += __shfl_xor(a2, 32, 64);
    a3 += __shfl_xor(a3, 32, 64);
    float dv = dinv[d];
    a0 = fmaxf(fmaf(a0, dv, b4.x), 0.f);
    a1 = fmaxf(fmaf(a1, dv, b4.y), 0.f);
    a2 = fmaxf(fmaf(a2, dv, b4.z), 0.f);
    a3 = fmaxf(fmaf(a3, dv, b4.w), 0.f);
    if (FINAL) {
      float r = a0 * w4.x + a1 * w4.y + a2 * w4.z + a3 * w4.w;
      r += __shfl_xor(r, 16, 64);
      r += __shfl_xor(r, 8, 64);
      r += __shfl_xor(r, 4, 64);
      r += __shfl_xor(r, 2, 64);
      r += __shfl_xor(r, 1, 64);
      if (lane == 0) ((float*)outp)[d] = 1.f / (1.f + __expf(-(r + bout[0])));
    } else {
      if (half == 0) {
        uint2 o;
        o.x = (unsigned)f2b(a0) | ((unsigned)f2b(a1) << 16);
        o.y = (unsigned)f2b(a2) | ((unsigned)f2b(a3) << 16);
        ((uint2*)outp)[d * 32 + li] = o;
      }
    }
  }
}

// ---------------------------------------------------------------------------
extern "C" void kernel_launch(void* const* d_in, const int* in_sizes, int n_in,
                              void* d_out, int out_size, void* d_ws, size_t ws_size,
                              hipStream_t stream) {
  const float* x  = (const float*)d_in[0];
  const void*  ei = d_in[1];
  const float* W1 = (const float*)d_in[2];
  const float* b1 = (const float*)d_in[3];
  const float* W2 = (const float*)d_in[4];
  const float* b2 = (const float*)d_in[5];
  const float* Wo = (const float*)d_in[6];
  const float* bo = (const float*)d_in[7];
  float* out = (float*)d_out;

  char* p = (char*)d_ws;
  auto alloc = [&](size_t bytes) {
    char* r = p;
    p += (bytes + 511) & ~(size_t)511;
    return r;
  };
  int*   bh     = (int*)alloc(sizeof(int) * NBUK * PBLK);
  int*   colsum = (int*)alloc(sizeof(int) * NBUK);
  int*   bstart = (int*)alloc(sizeof(int) * (NBUK + 1));
  int*   off    = (int*)alloc(sizeof(int) * (NN + 1));
  float* dinv   = (float*)alloc(sizeof(float) * NN);
  unsigned short* csr16 = (unsigned short*)alloc(sizeof(short) * NE);
  unsigned short* Wt1 = (unsigned short*)alloc(sizeof(short) * 128 * 128);
  unsigned short* Wt2 = (unsigned short*)alloc(sizeof(short) * 128 * 128);
  unsigned short* T   = (unsigned short*)alloc(sizeof(short) * (size_t)NN * 128);
  unsigned short* H   = (unsigned short*)alloc(sizeof(short) * (size_t)NN * 128);
  unsigned* epk = (unsigned*)T;  // 3.2 MB, dead before k_mgemm<1> writes T

  k_phist<<<PBLK, 256, 0, stream>>>(ei, bh);
  k_pscanA<<<NBUK, 256, 0, stream>>>(bh, colsum);
  k_pscanB<<<1, 256, 0, stream>>>(colsum, bstart);
  k_pscat<<<PBLK, 256, 0, stream>>>(ei, bh, bstart, epk);
  k_bofffill<<<NBUK, 256, 0, stream>>>(epk, bstart, off, dinv, csr16);
  k_wt2<<<128, 256, 0, stream>>>(W1, W2, Wt1, Wt2);

  k_mgemm<1><<<512, 256, 0, stream>>>(x, Wt1, dinv, T, NN);
  k_agg<0><<<2048, 256, 0, stream>>>(T, off, csr16, dinv, b1, nullptr, nullptr, H);
  k_mgemm<0><<<512, 256, 0, stream>>>(H, Wt2, dinv, T, NN);
  k_agg<1><<<2048, 256, 0, stream>>>(T, off, csr16, dinv, b2, Wo, bo, out);
}